// Round 11
// baseline (1839.087 us; speedup 1.0000x reference)
//
#include <hip/hip_runtime.h>
#include <hip/hip_bf16.h>

#define T_DIM 2048
#define B_DIM 16
#define D_DIM 1024
#define M_DIM (T_DIM * B_DIM)   // 32768 GEMM rows
#define K_DIM D_DIM             // 1024
#define N_DIM (3 * D_DIM)       // 3072 (cand_x | delta | gate)
#define BD (B_DIM * D_DIM)      // 16384 parallel chains
#define CHUNKS 64
#define CLEN (T_DIM / CHUNKS)   // 32
#define NT (K_DIM / 32)         // 32 K-tiles (BK=32)

typedef __attribute__((ext_vector_type(8))) short bf16x8;
typedef __attribute__((ext_vector_type(4))) float f32x4;
typedef __attribute__((ext_vector_type(4))) unsigned short us4;
typedef __attribute__((ext_vector_type(8))) unsigned short us8;

__device__ __forceinline__ unsigned short f2bf(float f) {
    unsigned int u = __builtin_bit_cast(unsigned int, f);
    u += 0x7fffu + ((u >> 16) & 1u);  // RNE
    return (unsigned short)(u >> 16);
}
__device__ __forceinline__ float bf2f(unsigned short s) {
    unsigned int u = ((unsigned int)s) << 16;
    return __builtin_bit_cast(float, u);
}
__device__ __forceinline__ float sigmoid_f(float x) {
    return __builtin_amdgcn_rcpf(1.0f + __expf(-x));
}
__device__ __forceinline__ float tanh_f(float x) {
    float e = __expf(2.0f * x);
    return 1.0f - 2.0f * __builtin_amdgcn_rcpf(e + 1.0f);
}

__device__ __forceinline__ void gload_lds16(const unsigned short* g, unsigned short* l) {
    __builtin_amdgcn_global_load_lds(
        (const __attribute__((address_space(1))) unsigned int*)g,
        (__attribute__((address_space(3))) unsigned int*)l, 16, 0, 0);
}

// swizzled ds_read of one bf16x8 from a [128 rows][32 K] half-slot (8 KB).
// byte addr = row*64 + (lk*16 ^ ((row&3)<<4)); 2-way bank aliasing = free.
__device__ __forceinline__ bf16x8 lds_rd(const unsigned short* ldsx, int slot, int srow, int lk) {
    int ce = (((lk * 16) ^ ((srow & 3) << 4)) >> 1);
    return *reinterpret_cast<const bf16x8*>(ldsx + slot * 4096 + srow * 32 + ce);
}

// ---------------------------------------------------------------------------
// Single merged f32 -> bf16 conversion for x, Wx, Wd, Wg (1 launch).
// ---------------------------------------------------------------------------
#define XN8 (M_DIM * K_DIM / 8)
#define WN8 (D_DIM * K_DIM / 8)
__global__ __launch_bounds__(256)
void conv_all(const float* __restrict__ x,  const float* __restrict__ Wx,
              const float* __restrict__ Wd, const float* __restrict__ Wg,
              unsigned short* __restrict__ xb, unsigned short* __restrict__ Wb)
{
    int i = blockIdx.x * 256 + threadIdx.x;
    const float* src;
    unsigned short* dst;
    int off;
    if (i < XN8)                { src = x;  dst = xb;               off = i; }
    else if (i < XN8 + WN8)     { src = Wx; dst = Wb;               off = i - XN8; }
    else if (i < XN8 + 2 * WN8) { src = Wd; dst = Wb + (size_t)WN8 * 8;     off = i - XN8 - WN8; }
    else                        { src = Wg; dst = Wb + (size_t)2 * WN8 * 8; off = i - XN8 - 2 * WN8; }
    const f32x4* p = reinterpret_cast<const f32x4*>(src) + (size_t)off * 2;
    f32x4 v0 = __builtin_nontemporal_load(p);
    f32x4 v1 = __builtin_nontemporal_load(p + 1);
    us8 w;
    w[0] = f2bf(v0[0]); w[1] = f2bf(v0[1]); w[2] = f2bf(v0[2]); w[3] = f2bf(v0[3]);
    w[4] = f2bf(v1[0]); w[5] = f2bf(v1[1]); w[6] = f2bf(v1[2]); w[7] = f2bf(v1[3]);
    *reinterpret_cast<us8*>(dst + (size_t)off * 8) = w;
}

// ---------------------------------------------------------------------------
// Fused projection GEMM — 256x256 tile, BK=32, 8 waves (2Mx4N), 64 KiB LDS
// => 2 BLOCKS PER CU (block-level stall overlap). A halves = wr partition,
// B halves = wc>>1 partition; 4 slots/operand ring over (tile parity, half).
// Counted vmcnt(2); swapped-operand MFMA; 2-pass LDS-staged nt epilogue.
// ---------------------------------------------------------------------------
__global__ __launch_bounds__(512, 4)
void gemm_fused(const unsigned short* __restrict__ xb,
                const unsigned short* __restrict__ Wb,
                const float* __restrict__ bx, const float* __restrict__ bdl,
                const float* __restrict__ bg,
                unsigned short* __restrict__ cxw, unsigned short* __restrict__ dw,
                unsigned short* __restrict__ gw)
{
    // 64 KiB LDS total: A = 4 slots x 4096 elems, B = same. Epilogue reuses
    // the whole 32768 elems as a 128x256 bf16 C half-tile.
    __shared__ unsigned short lds[8 * 4096];
    unsigned short* ldsA = lds;
    unsigned short* ldsB = lds + 4 * 4096;

    const int NWG = (M_DIM / 256) * (N_DIM / 256);   // 1536, %8 == 0
    int bid = blockIdx.x;
    int wg  = (bid & 7) * (NWG / 8) + (bid >> 3);    // XCD-bijective
    const int bidM = wg / 12;                        // M-outer per XCD
    const int bidN = wg % 12;                        // N inner: x-panel L2-resident
    const int tM  = bidM * 256;
    const int tN  = bidN * 256;
    const int arr = tN >> 10;
    const int nb  = tN & 1023;

    const float* bias = (arr == 0) ? bx : (arr == 1) ? bdl : bg;
    unsigned short* outp = (arr == 0) ? cxw : (arr == 1) ? dw : gw;

    const int tid  = threadIdx.x;
    const int lane = tid & 63;
    const int wid  = tid >> 6;
    const int wr = wid >> 2, wc = wid & 3;           // wave -> 128x64 output
    const int lr = lane & 15, lk = lane >> 4;

    const unsigned short* Asrc = xb + (size_t)tM * K_DIM;
    const unsigned short* Bsrc = Wb + (size_t)arr * (D_DIM * K_DIM) + (size_t)nb * K_DIM;

    // staging geometry: per wave 1 gload = 64 chunks of 16B = 16 rows x 32 K.
    // inverse swizzle on global source chunk position (both-sides involution).
    const int cidx = wid * 64 + lane;                // chunk id in half (0..511)
    const int srow = cidx >> 2;                      // row 0..127
    const int sk   = (((cidx & 3) ^ (srow & 3)) << 3); // src elem offset

    auto stA = [&](int t, int h) {
        int slot = 2 * (t & 1) + h;
        gload_lds16(Asrc + (size_t)(h * 128 + srow) * K_DIM + t * 32 + sk,
                    ldsA + slot * 4096 + wid * 512);
    };
    auto stB = [&](int t, int h) {
        int slot = 2 * (t & 1) + h;
        gload_lds16(Bsrc + (size_t)(h * 128 + srow) * K_DIM + t * 32 + sk,
                    ldsB + slot * 4096 + wid * 512);
    };

    f32x4 acc[8][4];
#pragma unroll
    for (int mi = 0; mi < 8; mi++)
#pragma unroll
        for (int ni = 0; ni < 4; ni++)
            acc[mi][ni] = (f32x4){0.f, 0.f, 0.f, 0.f};

    // Prologue: tile0 (A0,A1,B0,B1) + tile1 (B0,B1) => 6 loads/wave.
    stA(0, 0); stA(0, 1);
    stB(0, 0); stB(0, 1);
    stB(1, 0); stB(1, 1);
    asm volatile("s_waitcnt vmcnt(2)" ::: "memory");   // tile0 landed; B(1) in flight
    __builtin_amdgcn_s_barrier();

    const int brow = (wc & 1) * 64;
    bf16x8 bf[4], afP[2], afQ[2];

#define RD_AF(DST, P, ASLOT)                                                       \
    do {                                                                           \
        _Pragma("unroll") for (int j = 0; j < 2; j++)                              \
            DST[j] = lds_rd(ldsA, (ASLOT), (2 * (P) + j) * 16 + lr, lk);           \
    } while (0)

#define RD_BF(BSLOT)                                                               \
    do {                                                                           \
        _Pragma("unroll") for (int ni = 0; ni < 4; ni++)                           \
            bf[ni] = lds_rd(ldsB, (BSLOT), brow + ni * 16 + lr, lk);               \
    } while (0)

// operand-swapped: acc = bf * af  => acc holds C^T quadrants.
#define MFMA8(P, AF)                                                               \
    do {                                                                           \
        __builtin_amdgcn_s_setprio(1);                                             \
        _Pragma("unroll") for (int j = 0; j < 2; j++)                              \
            _Pragma("unroll") for (int ni = 0; ni < 4; ni++)                       \
                acc[2 * (P) + j][ni] = __builtin_amdgcn_mfma_f32_16x16x32_bf16(    \
                    bf[ni], AF[j], acc[2 * (P) + j][ni], 0, 0, 0);                 \
        __builtin_amdgcn_s_setprio(0);                                             \
    } while (0)

#define BAR __builtin_amdgcn_s_barrier()

// Hazard ledger (reader -> overwriter), each >=1 barrier apart:
//  A(t-1,h) reads end @(t-1)ph2, retired by MFMA8(3)@(t-1)ph3 lgkm;
//    stA(t+1,h0)@(t)ph0 / h1@(t)ph1 are past (t-1)'s trailing BAR.   OK
//  B(t) reads @(t-1)ph3, retired by MFMA8(0)@(t)ph0 lgkm;
//    stB(t+2,h)@(t)ph2/ph3 are >=2 BARs later.                        OK
//  ph3 frag reads need A(t+1) (staged ph0/ph1) + B(t+1) (staged t-1):
//    vmcnt(2) leaves only B(t+2) x2 in flight; BAR publishes.         OK
//  MFMA8(3) precedes RD_BF (bf register WAR — the R9 lesson).         OK
#define TILE(KT, PAR, LAST)                                                        \
    do {                                                                           \
        const int aslot = 2 * (PAR) + wr;                                          \
        /* ph0 */                                                                  \
        if ((KT) + 1 < NT) stA((KT) + 1, 0);                                       \
        RD_AF(afQ, 1, aslot);                                                      \
        MFMA8(0, afP);                                                             \
        BAR;                                                                       \
        /* ph1 */                                                                  \
        if ((KT) + 1 < NT) stA((KT) + 1, 1);                                       \
        RD_AF(afP, 2, aslot);                                                      \
        MFMA8(1, afQ);                                                             \
        BAR;                                                                       \
        /* ph2 */                                                                  \
        if ((KT) + 2 < NT) stB((KT) + 2, 0);                                       \
        RD_AF(afQ, 3, aslot);                                                      \
        MFMA8(2, afP);                                                             \
        BAR;                                                                       \
        /* ph3 */                                                                  \
        if ((KT) + 2 < NT) stB((KT) + 2, 1);                                       \
        if ((KT) < NT - 2) asm volatile("s_waitcnt vmcnt(2)" ::: "memory");        \
        else               asm volatile("s_waitcnt vmcnt(0)" ::: "memory");        \
        BAR;                                                                       \
        MFMA8(3, afQ);                                                             \
        if (!(LAST)) {                                                             \
            RD_BF(2 * (1 - (PAR)) + (wc >> 1));                                    \
            RD_AF(afP, 0, 2 * (1 - (PAR)) + wr);                                   \
        }                                                                          \
        BAR;                                                                       \
    } while (0)

    // initial fragment fill for tile 0 (par = 0)
    RD_BF(wc >> 1);
    RD_AF(afP, 0, wr);

    for (int kt = 0; kt < NT; kt += 2) {
        TILE(kt, 0, false);
        TILE(kt + 1, 1, (kt + 1 == NT - 1));
    }

    // ---- Epilogue: 2 passes of 128 rows through the 64 KB LDS C half-tile;
    //      acc = C^T quadrants -> packed b64 swizzled LDS writes, then
    //      fully-coalesced nontemporal 16B global stores.
#pragma unroll
    for (int half = 0; half < 2; half++) {
        __syncthreads();
        if (wr == half) {
#pragma unroll
            for (int mi = 0; mi < 8; mi++) {
                int rl = mi * 16 + lr;                // local row in half
#pragma unroll
                for (int ni = 0; ni < 4; ni++) {
                    int col0 = wc * 64 + ni * 16 + lk * 4;
                    f32x4 bia = *reinterpret_cast<const f32x4*>(bias + nb + col0);
                    us4 w;
#pragma unroll
                    for (int r = 0; r < 4; r++) {
                        float v = acc[mi][ni][r] + bia[r];
                        if (arr == 1)      v = sigmoid_f(v);
                        else if (arr == 2) v = v * sigmoid_f(v);
                        w[r] = f2bf(v);
                    }
                    int byte = (rl * 512 + col0 * 2) ^ ((rl & 7) << 4);
                    *reinterpret_cast<us4*>(reinterpret_cast<char*>(lds) + byte) = w;
                }
            }
        }
        __syncthreads();
#pragma unroll
        for (int it = 0; it < 8; ++it) {
            int off8 = it * 512 + tid;              // 4096 chunks of 16B
            int rl   = off8 >> 5;
            int col8 = (off8 & 31) << 3;
            int byte = (rl * 512 + col8 * 2) ^ ((rl & 7) << 4);
            us8 v = *reinterpret_cast<const us8*>(reinterpret_cast<char*>(lds) + byte);
            __builtin_nontemporal_store(v,
                reinterpret_cast<us8*>(outp + (size_t)(tM + half * 128 + rl) * D_DIM + nb + col8));
        }
    }
#undef RD_AF
#undef RD_BF
#undef MFMA8
#undef BAR
#undef TILE
}

// ---------------------------------------------------------------------------
// Scan pass 1: per (chunk, channel-quad): A = prod(1-d), B = local scan from 0
// ---------------------------------------------------------------------------
__global__ __launch_bounds__(256)
void scan_pass1(const unsigned short* __restrict__ dw,
                const unsigned short* __restrict__ cxw,
                float* __restrict__ Aw, float* __restrict__ Bw)
{
    int g  = blockIdx.x * 256 + threadIdx.x;
    int c  = g / (BD / 4);
    int i0 = (g % (BD / 4)) * 4;
    size_t base = (size_t)c * CLEN * BD + i0;

    float a[4]  = {1.f, 1.f, 1.f, 1.f};
    float hb[4] = {0.f, 0.f, 0.f, 0.f};
    for (int t = 0; t < CLEN; t++) {
        us4 dv = *reinterpret_cast<const us4*>(dw  + base + (size_t)t * BD);
        us4 cv = *reinterpret_cast<const us4*>(cxw + base + (size_t)t * BD);
#pragma unroll
        for (int j = 0; j < 4; j++) {
            float d = bf2f(dv[j]);
            float om = 1.f - d;
            float cand = tanh_f(bf2f(cv[j]));
            hb[j] = om * hb[j] + d * cand;
            a[j] *= om;
        }
    }
    f32x4 av = {a[0], a[1], a[2], a[3]};
    f32x4 bv = {hb[0], hb[1], hb[2], hb[3]};
    *reinterpret_cast<f32x4*>(Aw + (size_t)c * BD + i0) = av;
    *reinterpret_cast<f32x4*>(Bw + (size_t)c * BD + i0) = bv;
}

// ---------------------------------------------------------------------------
// Scan pass 2: sequential combine over chunks (tiny). Writes h[0].
// ---------------------------------------------------------------------------
__global__ __launch_bounds__(256)
void scan_pass2(const float* __restrict__ Aw, const float* __restrict__ Bw,
                const float* __restrict__ h0, float* __restrict__ hin,
                float* __restrict__ hseq)
{
    int i0 = (blockIdx.x * 256 + threadIdx.x) * 4;
    if (i0 >= BD) return;
    f32x4 h = *reinterpret_cast<const f32x4*>(h0 + i0);
    *reinterpret_cast<f32x4*>(hseq + i0) = h;
    for (int c = 0; c < CHUNKS; c++) {
        *reinterpret_cast<f32x4*>(hin + (size_t)c * BD + i0) = h;
        f32x4 A  = *reinterpret_cast<const f32x4*>(Aw + (size_t)c * BD + i0);
        f32x4 Bv = *reinterpret_cast<const f32x4*>(Bw + (size_t)c * BD + i0);
        h = A * h + Bv;
    }
}

// ---------------------------------------------------------------------------
// Scan pass 3: replay each chunk with true h_in; nt-store out and h.
// ---------------------------------------------------------------------------
__global__ __launch_bounds__(256)
void scan_pass3(const unsigned short* __restrict__ dw,
                const unsigned short* __restrict__ cxw,
                const unsigned short* __restrict__ gw,
                const float* __restrict__ hin,
                float* __restrict__ out, float* __restrict__ hseq)
{
    int g  = blockIdx.x * 256 + threadIdx.x;
    int c  = g / (BD / 4);
    int i0 = (g % (BD / 4)) * 4;
    size_t base = (size_t)c * CLEN * BD + i0;

    f32x4 h4 = *reinterpret_cast<const f32x4*>(hin + (size_t)c * BD + i0);
    float h[4] = {h4[0], h4[1], h4[2], h4[3]};
    for (int t = 0; t < CLEN; t++) {
        size_t idx = base + (size_t)t * BD;
        us4 dv = *reinterpret_cast<const us4*>(dw  + idx);
        us4 cv = *reinterpret_cast<const us4*>(cxw + idx);
        us4 gv = *reinterpret_cast<const us4*>(gw  + idx);
        f32x4 o, hv;
#pragma unroll
        for (int j = 0; j < 4; j++) {
            float d = bf2f(dv[j]);
            float om = 1.f - d;
            float cand = tanh_f(bf2f(cv[j]));
            h[j] = om * h[j] + d * cand;
            o[j] = h[j] * bf2f(gv[j]);
            hv[j] = h[j];
        }
        __builtin_nontemporal_store(o,  reinterpret_cast<f32x4*>(out + idx));
        __builtin_nontemporal_store(hv, reinterpret_cast<f32x4*>(hseq + idx + BD));
    }
}

// ---------------------------------------------------------------------------
// Fixup for channels with r_h != 0 (r_h == 0 here -> immediate exit).
// ---------------------------------------------------------------------------
__global__ __launch_bounds__(256)
void scan_fixup(const float* __restrict__ rh, const float* __restrict__ h0,
                const unsigned short* __restrict__ dw,
                const unsigned short* __restrict__ cxw,
                const unsigned short* __restrict__ gw,
                float* __restrict__ out, float* __restrict__ hseq)
{
    int i = blockIdx.x * 256 + threadIdx.x;
    if (i >= BD) return;
    float r = rh[i & (D_DIM - 1)];
    if (r == 0.0f) return;
    float h = h0[i];
    for (int t = 0; t < T_DIM; t++) {
        size_t idx = (size_t)t * BD + i;
        float d = bf2f(dw[idx]);
        float cand = tanh_f(bf2f(cxw[idx]) + r * h);
        h = (1.f - d) * h + d * cand;
        out[idx] = h * bf2f(gw[idx]);
        hseq[idx + BD] = h;
    }
}

extern "C" void kernel_launch(void* const* d_in, const int* in_sizes, int n_in,
                              void* d_out, int out_size, void* d_ws, size_t ws_size,
                              hipStream_t stream)
{
    const float* x   = (const float*)d_in[0];
    const float* h0  = (const float*)d_in[1];
    const float* Wx  = (const float*)d_in[2];
    const float* rh  = (const float*)d_in[3];
    const float* Wd  = (const float*)d_in[4];
    const float* Wg  = (const float*)d_in[5];
    const float* bx  = (const float*)d_in[6];
    const float* bdl = (const float*)d_in[7];
    const float* bg  = (const float*)d_in[8];

    float* out  = (float*)d_out;                       // [T,B,D]
    float* hseq = out + (size_t)T_DIM * BD;            // [T+1,B,D]

    unsigned short* dw  = (unsigned short*)d_ws;
    unsigned short* cxw = dw  + (size_t)M_DIM * D_DIM;
    unsigned short* gw  = cxw + (size_t)M_DIM * D_DIM;
    float* Aw  = (float*)(gw + (size_t)M_DIM * D_DIM);
    float* Bw  = Aw + (size_t)CHUNKS * BD;
    float* hin = Bw + (size_t)CHUNKS * BD;

    // bf16 x and W live in the not-yet-written `out` region (GEMM finishes
    // before scan_pass3 writes out). 67.1 MB + 6.3 MB < 134 MB.
    unsigned short* xb = (unsigned short*)d_out;
    unsigned short* Wb = xb + (size_t)M_DIM * K_DIM;

    conv_all<<<dim3((XN8 + 3 * WN8) / 256), dim3(256), 0, stream>>>(x, Wx, Wd, Wg, xb, Wb);

    gemm_fused<<<dim3((M_DIM / 256) * (N_DIM / 256)), dim3(512), 0, stream>>>(
        xb, Wb, bx, bdl, bg, cxw, dw, gw);

    scan_pass1<<<dim3(CHUNKS * BD / 4 / 256), dim3(256), 0, stream>>>(dw, cxw, Aw, Bw);
    scan_pass2<<<dim3(BD / 4 / 256 + 1), dim3(256), 0, stream>>>(Aw, Bw, h0, hin, hseq);
    scan_pass3<<<dim3(CHUNKS * BD / 4 / 256), dim3(256), 0, stream>>>(dw, cxw, gw, hin, out, hseq);
    scan_fixup<<<dim3(BD / 256), dim3(256), 0, stream>>>(rh, h0, dw, cxw, gw, out, hseq);
}

// Round 12
// 371.217 us; speedup vs baseline: 4.9542x; 4.9542x over previous
//
#include <hip/hip_runtime.h>
#include <hip/hip_bf16.h>

#define T_DIM 2048
#define B_DIM 16
#define D_DIM 1024
#define M_DIM (T_DIM * B_DIM)   // 32768 GEMM rows
#define K_DIM D_DIM             // 1024
#define N_DIM (3 * D_DIM)       // 3072 (cand_x | delta | gate)
#define BD (B_DIM * D_DIM)      // 16384 parallel chains
#define CHUNKS 64
#define CLEN (T_DIM / CHUNKS)   // 32
#define NT (K_DIM / 64)         // 16 K-tiles (BK=64)

typedef __attribute__((ext_vector_type(8))) short bf16x8;
typedef __attribute__((ext_vector_type(4))) float f32x4;
typedef __attribute__((ext_vector_type(4))) unsigned short us4;
typedef __attribute__((ext_vector_type(8))) unsigned short us8;

__device__ __forceinline__ unsigned short f2bf(float f) {
    unsigned int u = __builtin_bit_cast(unsigned int, f);
    u += 0x7fffu + ((u >> 16) & 1u);  // RNE
    return (unsigned short)(u >> 16);
}
__device__ __forceinline__ float bf2f(unsigned short s) {
    unsigned int u = ((unsigned int)s) << 16;
    return __builtin_bit_cast(float, u);
}
__device__ __forceinline__ float sigmoid_f(float x) {
    return __builtin_amdgcn_rcpf(1.0f + __expf(-x));
}
__device__ __forceinline__ float tanh_f(float x) {
    float e = __expf(2.0f * x);
    return 1.0f - 2.0f * __builtin_amdgcn_rcpf(e + 1.0f);
}

__device__ __forceinline__ void gload_lds16(const unsigned short* g, unsigned short* l) {
    __builtin_amdgcn_global_load_lds(
        (const __attribute__((address_space(1))) unsigned int*)g,
        (__attribute__((address_space(3))) unsigned int*)l, 16, 0, 0);
}

// swizzled ds_read of one bf16x8 fragment slice from a 128x64 half-slot
__device__ __forceinline__ bf16x8 lds_rd(const unsigned short* lds, int slot, int srow, int kk, int lk) {
    int ce = (((kk * 64) + (lk * 16)) ^ ((srow & 7) << 4)) >> 1;   // byte-swizzle -> elem
    return *reinterpret_cast<const bf16x8*>(lds + slot * 8192 + srow * 64 + ce);
}

// ---------------------------------------------------------------------------
// Single merged f32 -> bf16 conversion for x, Wx, Wd, Wg (1 launch).
// ---------------------------------------------------------------------------
#define XN8 (M_DIM * K_DIM / 8)
#define WN8 (D_DIM * K_DIM / 8)
__global__ __launch_bounds__(256)
void conv_all(const float* __restrict__ x,  const float* __restrict__ Wx,
              const float* __restrict__ Wd, const float* __restrict__ Wg,
              unsigned short* __restrict__ xb, unsigned short* __restrict__ Wb)
{
    int i = blockIdx.x * 256 + threadIdx.x;
    const float* src;
    unsigned short* dst;
    int off;
    if (i < XN8)                { src = x;  dst = xb;               off = i; }
    else if (i < XN8 + WN8)     { src = Wx; dst = Wb;               off = i - XN8; }
    else if (i < XN8 + 2 * WN8) { src = Wd; dst = Wb + (size_t)WN8 * 8;     off = i - XN8 - WN8; }
    else                        { src = Wg; dst = Wb + (size_t)2 * WN8 * 8; off = i - XN8 - 2 * WN8; }
    const f32x4* p = reinterpret_cast<const f32x4*>(src) + (size_t)off * 2;
    f32x4 v0 = __builtin_nontemporal_load(p);
    f32x4 v1 = __builtin_nontemporal_load(p + 1);
    us8 w;
    w[0] = f2bf(v0[0]); w[1] = f2bf(v0[1]); w[2] = f2bf(v0[2]); w[3] = f2bf(v0[3]);
    w[4] = f2bf(v1[0]); w[5] = f2bf(v1[1]); w[6] = f2bf(v1[2]); w[7] = f2bf(v1[3]);
    *reinterpret_cast<us8*>(dst + (size_t)off * 8) = w;
}

// ---------------------------------------------------------------------------
// Fused projection GEMM — 256x256 tile, BK=64, 8 waves (2Mx4N).
// TWO barriers per K-tile, 32-MFMA clusters: {stage; read 8 af; 32 MFMA; BAR}
// x2, with counted vmcnt(6)+BAR before the cross-wave bf prefetch (the only
// cross-wave-visibility-dependent read). Staging/slot schedule = verified R7.
// Register budget: acc 128 + af 32 + bf 32 + addr ~= 240 < 256 @ (512,2).
// ---------------------------------------------------------------------------
__global__ __launch_bounds__(512, 2)
void gemm_fused(const unsigned short* __restrict__ xb,
                const unsigned short* __restrict__ Wb,
                const float* __restrict__ bx, const float* __restrict__ bdl,
                const float* __restrict__ bg,
                unsigned short* __restrict__ cxw, unsigned short* __restrict__ dw,
                unsigned short* __restrict__ gw)
{
    // 128 KiB LDS: K-loop = 4 half-slots x 16KB per operand; epilogue = C-tile
    __shared__ unsigned short lds[8 * 8192];
    unsigned short* ldsA = lds;
    unsigned short* ldsB = lds + 4 * 8192;

    const int NWG = (M_DIM / 256) * (N_DIM / 256);   // 1536, %8 == 0
    int bid = blockIdx.x;
    int wg  = (bid & 7) * (NWG / 8) + (bid >> 3);    // XCD-bijective
    const int bidM = wg / 12;                        // M-outer per XCD
    const int bidN = wg % 12;                        // N inner: x-panel L2-resident
    const int tM  = bidM * 256;
    const int tN  = bidN * 256;
    const int arr = tN >> 10;
    const int nb  = tN & 1023;

    const float* bias = (arr == 0) ? bx : (arr == 1) ? bdl : bg;
    unsigned short* outp = (arr == 0) ? cxw : (arr == 1) ? dw : gw;

    const int tid  = threadIdx.x;
    const int lane = tid & 63;
    const int wid  = tid >> 6;
    const int wr = wid >> 2, wc = wid & 3;           // wave -> 128x64 output
    const int lr = lane & 15, lk = lane >> 4;

    const unsigned short* Asrc = xb + (size_t)tM * K_DIM;
    const unsigned short* Bsrc = Wb + (size_t)arr * (D_DIM * K_DIM) + (size_t)nb * K_DIM;

    // staging source geometry (T2 inverse swizzle on the global address)
    const int t8 = tid >> 3;                              // 0..63
    const int ke = (((tid & 7) ^ (t8 & 7)) << 3);         // k-elem offset
    auto arow = [&](int h, int w) {
        int s = w * 64 + t8;
        return ((s >> 4) & 1) * 128 + (h * 4 + (s >> 5)) * 16 + (s & 15);
    };
    const int rA00 = arow(0, 0), rA01 = arow(0, 1);
    const int rA10 = arow(1, 0), rA11 = arow(1, 1);

    auto stA = [&](int t, int r0, int r1, int slot) {
        gload_lds16(Asrc + (size_t)r0 * K_DIM + t * 64 + ke, ldsA + slot * 8192 + wid * 512);
        gload_lds16(Asrc + (size_t)r1 * K_DIM + t * 64 + ke, ldsA + slot * 8192 + 4096 + wid * 512);
    };
    auto stB = [&](int t, int h, int slot) {
        gload_lds16(Bsrc + (size_t)(h * 128 + t8) * K_DIM + t * 64 + ke,      ldsB + slot * 8192 + wid * 512);
        gload_lds16(Bsrc + (size_t)(h * 128 + 64 + t8) * K_DIM + t * 64 + ke, ldsB + slot * 8192 + 4096 + wid * 512);
    };

    f32x4 acc[8][4];
#pragma unroll
    for (int mi = 0; mi < 8; mi++)
#pragma unroll
        for (int ni = 0; ni < 4; ni++)
            acc[mi][ni] = (f32x4){0.f, 0.f, 0.f, 0.f};

    // Prologue: tile0 (4 halves) + tile1 {A0, B0, B1} => 14 loads/wave
    stA(0, rA00, rA01, 0);
    stA(0, rA10, rA11, 1);
    stB(0, 0, 0);
    stB(0, 1, 1);
    stA(1, rA00, rA01, 2);
    stB(1, 0, 2);
    stB(1, 1, 3);
    asm volatile("s_waitcnt vmcnt(0)" ::: "memory");
    __builtin_amdgcn_s_barrier();

    const int brow = (wc & 1) * 64;
    bf16x8 bf[4][2], af[4][2];

// read all 8 A-frag slices for one half (mi group): rows {0,32,64,96}+wr*16+lr
#define RD_AF8(ASLOT)                                                              \
    do {                                                                           \
        _Pragma("unroll") for (int m4 = 0; m4 < 4; m4++)                           \
            _Pragma("unroll") for (int kk = 0; kk < 2; kk++)                       \
                af[m4][kk] = lds_rd(ldsA, (ASLOT), m4 * 32 + wr * 16 + lr, kk, lk); \
    } while (0)

#define RD_BF(BSLOT)                                                               \
    do {                                                                           \
        _Pragma("unroll") for (int ni = 0; ni < 4; ni++)                           \
            _Pragma("unroll") for (int kk = 0; kk < 2; kk++)                       \
                bf[ni][kk] = lds_rd(ldsB, (BSLOT), brow + ni * 16 + lr, kk, lk);   \
    } while (0)

// operand-swapped: acc = bf * af => acc holds C^T quadrants. 32 MFMA cluster.
#define MFMA32(HALF)                                                               \
    do {                                                                           \
        __builtin_amdgcn_s_setprio(1);                                             \
        _Pragma("unroll") for (int m4 = 0; m4 < 4; m4++)                           \
            _Pragma("unroll") for (int ni = 0; ni < 4; ni++) {                     \
                acc[(HALF) * 4 + m4][ni] = __builtin_amdgcn_mfma_f32_16x16x32_bf16( \
                    bf[ni][0], af[m4][0], acc[(HALF) * 4 + m4][ni], 0, 0, 0);      \
                acc[(HALF) * 4 + m4][ni] = __builtin_amdgcn_mfma_f32_16x16x32_bf16( \
                    bf[ni][1], af[m4][1], acc[(HALF) * 4 + m4][ni], 0, 0, 0);      \
            }                                                                      \
        __builtin_amdgcn_s_setprio(0);                                             \
    } while (0)

#define BAR __builtin_amdgcn_s_barrier()

// Hazard ledger (reader -> overwriter), each >=1 barrier apart:
//  A(t,h0): last read RD_AF8@P0(t), lgkm-retired before MFMA32(0) issues ->
//    before wave crosses BAR(P0); stA(t+2,h0)@P1(t) is after that BAR.   OK
//  A(t,h1): last read RD_AF8@P1(t), retired before MFMA32(1);
//    stA(t+2,h1)... staged as A(t'+1,h1)@P0(t+1), after BAR(P1(t)).      OK
//  B(t): bf reads @P1(t-1) tail, retired before MFMA32(0)@P0(t) (first bf
//    use) -> before BAR(P0(t)); stB(t+2,h)@P1(t) after that BAR.         OK
//  RD_BF(t+1)@P1(t) tail: B(t+1) staged @P1(t-1); vmcnt(6)@P1(t) retains
//    only P1(t)'s own 6 stages -> all P1(t-1) stages drained; BAR
//    publishes cross-wave.                                               OK
//  RD_AF8(a1s)@P1(t): A(t,h1) staged @P0(t-1); drained by vmcnt(6)@P1(t-1)
//    (retains P1(t-1)'s 6, drains P0(t-1)'s 2) + BAR(P1(t-1)).           OK
//  bf register WAR: RD_BF after MFMA32(1) in program order.              OK
#define TILE(KT, PAR, LAST)                                                        \
    do {                                                                           \
        const int a0s = 2 * (PAR), a1s = 2 * (PAR) + 1;                            \
        /* P0: stage A(t+1,h1); read af(h0); 32 MFMA (mi0-3) */                    \
        if ((KT) + 1 < NT) stA((KT) + 1, rA10, rA11, 2 * (1 - (PAR)) + 1);         \
        RD_AF8(a0s);                                                               \
        MFMA32(0);                                                                 \
        BAR;                                                                       \
        /* P1: stage A/B(t+2); read af(h1); 32 MFMA (mi4-7); vmcnt; BAR; bf */     \
        if ((KT) + 2 < NT) {                                                       \
            stA((KT) + 2, rA00, rA01, a0s);                                        \
            stB((KT) + 2, 0, a0s);                                                 \
            stB((KT) + 2, 1, a1s);                                                 \
        }                                                                          \
        RD_AF8(a1s);                                                               \
        MFMA32(1);                                                                 \
        if ((KT) < NT - 2) asm volatile("s_waitcnt vmcnt(6)" ::: "memory");        \
        else               asm volatile("s_waitcnt vmcnt(0)" ::: "memory");        \
        BAR;                                                                       \
        if (!(LAST)) RD_BF(2 * (1 - (PAR)) + (wc >> 1));                           \
    } while (0)

    // initial bf fill for tile 0
    RD_BF(wc >> 1);

    for (int kt = 0; kt < NT; kt += 2) {
        TILE(kt, 0, false);
        TILE(kt + 1, 1, (kt + 1 == NT - 1));
    }

    // ---- Epilogue: acc = C^T quadrants -> packed b64 swizzled LDS stores,
    //      then fully-coalesced nontemporal 16B global stores.
#pragma unroll
    for (int mi = 0; mi < 8; mi++) {
        int row = wr * 128 + mi * 16 + lr;        // C-row (local 0..255)
#pragma unroll
        for (int ni = 0; ni < 4; ni++) {
            int col0 = wc * 64 + ni * 16 + lk * 4; // 4 consecutive C-cols
            f32x4 bia = *reinterpret_cast<const f32x4*>(bias + nb + col0);
            us4 w;
#pragma unroll
            for (int r = 0; r < 4; r++) {
                float v = acc[mi][ni][r] + bia[r];
                if (arr == 1)      v = sigmoid_f(v);
                else if (arr == 2) v = v * sigmoid_f(v);
                w[r] = f2bf(v);
            }
            int byte = (row * 512 + col0 * 2) ^ ((row & 7) << 4);
            *reinterpret_cast<us4*>(reinterpret_cast<char*>(lds) + byte) = w;
        }
    }
    __syncthreads();
#pragma unroll
    for (int it = 0; it < 16; ++it) {
        int off8 = it * 512 + tid;              // 16B-chunk id, 8192 total
        int row  = off8 >> 5;                   // 32 chunks per 256-col row
        int col8 = (off8 & 31) << 3;
        int byte = (row * 512 + col8 * 2) ^ ((row & 7) << 4);
        us8 v = *reinterpret_cast<const us8*>(reinterpret_cast<char*>(lds) + byte);
        __builtin_nontemporal_store(v,
            reinterpret_cast<us8*>(outp + (size_t)(tM + row) * D_DIM + nb + col8));
    }
#undef RD_AF8
#undef RD_BF
#undef MFMA32
#undef BAR
#undef TILE
}

// ---------------------------------------------------------------------------
// Scan pass 1: per (chunk, channel-quad): A = prod(1-d), B = local scan from 0
// ---------------------------------------------------------------------------
__global__ __launch_bounds__(256)
void scan_pass1(const unsigned short* __restrict__ dw,
                const unsigned short* __restrict__ cxw,
                float* __restrict__ Aw, float* __restrict__ Bw)
{
    int g  = blockIdx.x * 256 + threadIdx.x;
    int c  = g / (BD / 4);
    int i0 = (g % (BD / 4)) * 4;
    size_t base = (size_t)c * CLEN * BD + i0;

    float a[4]  = {1.f, 1.f, 1.f, 1.f};
    float hb[4] = {0.f, 0.f, 0.f, 0.f};
    for (int t = 0; t < CLEN; t++) {
        us4 dv = *reinterpret_cast<const us4*>(dw  + base + (size_t)t * BD);
        us4 cv = *reinterpret_cast<const us4*>(cxw + base + (size_t)t * BD);
#pragma unroll
        for (int j = 0; j < 4; j++) {
            float d = bf2f(dv[j]);
            float om = 1.f - d;
            float cand = tanh_f(bf2f(cv[j]));
            hb[j] = om * hb[j] + d * cand;
            a[j] *= om;
        }
    }
    f32x4 av = {a[0], a[1], a[2], a[3]};
    f32x4 bv = {hb[0], hb[1], hb[2], hb[3]};
    *reinterpret_cast<f32x4*>(Aw + (size_t)c * BD + i0) = av;
    *reinterpret_cast<f32x4*>(Bw + (size_t)c * BD + i0) = bv;
}

// ---------------------------------------------------------------------------
// Scan pass 2: sequential combine over chunks (tiny). Writes h[0].
// ---------------------------------------------------------------------------
__global__ __launch_bounds__(256)
void scan_pass2(const float* __restrict__ Aw, const float* __restrict__ Bw,
                const float* __restrict__ h0, float* __restrict__ hin,
                float* __restrict__ hseq)
{
    int i0 = (blockIdx.x * 256 + threadIdx.x) * 4;
    if (i0 >= BD) return;
    f32x4 h = *reinterpret_cast<const f32x4*>(h0 + i0);
    *reinterpret_cast<f32x4*>(hseq + i0) = h;
    for (int c = 0; c < CHUNKS; c++) {
        *reinterpret_cast<f32x4*>(hin + (size_t)c * BD + i0) = h;
        f32x4 A  = *reinterpret_cast<const f32x4*>(Aw + (size_t)c * BD + i0);
        f32x4 Bv = *reinterpret_cast<const f32x4*>(Bw + (size_t)c * BD + i0);
        h = A * h + Bv;
    }
}

// ---------------------------------------------------------------------------
// Scan pass 3: replay each chunk with true h_in; nt-store out and h.
// ---------------------------------------------------------------------------
__global__ __launch_bounds__(256)
void scan_pass3(const unsigned short* __restrict__ dw,
                const unsigned short* __restrict__ cxw,
                const unsigned short* __restrict__ gw,
                const float* __restrict__ hin,
                float* __restrict__ out, float* __restrict__ hseq)
{
    int g  = blockIdx.x * 256 + threadIdx.x;
    int c  = g / (BD / 4);
    int i0 = (g % (BD / 4)) * 4;
    size_t base = (size_t)c * CLEN * BD + i0;

    f32x4 h4 = *reinterpret_cast<const f32x4*>(hin + (size_t)c * BD + i0);
    float h[4] = {h4[0], h4[1], h4[2], h4[3]};
    for (int t = 0; t < CLEN; t++) {
        size_t idx = base + (size_t)t * BD;
        us4 dv = *reinterpret_cast<const us4*>(dw  + idx);
        us4 cv = *reinterpret_cast<const us4*>(cxw + idx);
        us4 gv = *reinterpret_cast<const us4*>(gw  + idx);
        f32x4 o, hv;
#pragma unroll
        for (int j = 0; j < 4; j++) {
            float d = bf2f(dv[j]);
            float om = 1.f - d;
            float cand = tanh_f(bf2f(cv[j]));
            h[j] = om * h[j] + d * cand;
            o[j] = h[j] * bf2f(gv[j]);
            hv[j] = h[j];
        }
        __builtin_nontemporal_store(o,  reinterpret_cast<f32x4*>(out + idx));
        __builtin_nontemporal_store(hv, reinterpret_cast<f32x4*>(hseq + idx + BD));
    }
}

// ---------------------------------------------------------------------------
// Fixup for channels with r_h != 0 (r_h == 0 here -> immediate exit).
// ---------------------------------------------------------------------------
__global__ __launch_bounds__(256)
void scan_fixup(const float* __restrict__ rh, const float* __restrict__ h0,
                const unsigned short* __restrict__ dw,
                const unsigned short* __restrict__ cxw,
                const unsigned short* __restrict__ gw,
                float* __restrict__ out, float* __restrict__ hseq)
{
    int i = blockIdx.x * 256 + threadIdx.x;
    if (i >= BD) return;
    float r = rh[i & (D_DIM - 1)];
    if (r == 0.0f) return;
    float h = h0[i];
    for (int t = 0; t < T_DIM; t++) {
        size_t idx = (size_t)t * BD + i;
        float d = bf2f(dw[idx]);
        float cand = tanh_f(bf2f(cxw[idx]) + r * h);
        h = (1.f - d) * h + d * cand;
        out[idx] = h * bf2f(gw[idx]);
        hseq[idx + BD] = h;
    }
}

extern "C" void kernel_launch(void* const* d_in, const int* in_sizes, int n_in,
                              void* d_out, int out_size, void* d_ws, size_t ws_size,
                              hipStream_t stream)
{
    const float* x   = (const float*)d_in[0];
    const float* h0  = (const float*)d_in[1];
    const float* Wx  = (const float*)d_in[2];
    const float* rh  = (const float*)d_in[3];
    const float* Wd  = (const float*)d_in[4];
    const float* Wg  = (const float*)d_in[5];
    const float* bx  = (const float*)d_in[6];
    const float* bdl = (const float*)d_in[7];
    const float* bg  = (const float*)d_in[8];

    float* out  = (float*)d_out;                       // [T,B,D]
    float* hseq = out + (size_t)T_DIM * BD;            // [T+1,B,D]

    unsigned short* dw  = (unsigned short*)d_ws;
    unsigned short* cxw = dw  + (size_t)M_DIM * D_DIM;
    unsigned short* gw  = cxw + (size_t)M_DIM * D_DIM;
    float* Aw  = (float*)(gw + (size_t)M_DIM * D_DIM);
    float* Bw  = Aw + (size_t)CHUNKS * BD;
    float* hin = Bw + (size_t)CHUNKS * BD;

    // bf16 x and W live in the not-yet-written `out` region (GEMM finishes
    // before scan_pass3 writes out). 67.1 MB + 6.3 MB < 134 MB.
    unsigned short* xb = (unsigned short*)d_out;
    unsigned short* Wb = xb + (size_t)M_DIM * K_DIM;

    conv_all<<<dim3((XN8 + 3 * WN8) / 256), dim3(256), 0, stream>>>(x, Wx, Wd, Wg, xb, Wb);

    gemm_fused<<<dim3((M_DIM / 256) * (N_DIM / 256)), dim3(512), 0, stream>>>(
        xb, Wb, bx, bdl, bg, cxw, dw, gw);

    scan_pass1<<<dim3(CHUNKS * BD / 4 / 256), dim3(256), 0, stream>>>(dw, cxw, Aw, Bw);
    scan_pass2<<<dim3(BD / 4 / 256 + 1), dim3(256), 0, stream>>>(Aw, Bw, h0, hin, hseq);
    scan_pass3<<<dim3(CHUNKS * BD / 4 / 256), dim3(256), 0, stream>>>(dw, cxw, gw, hin, out, hseq);
    scan_fixup<<<dim3(BD / 256), dim3(256), 0, stream>>>(rh, h0, dw, cxw, gw, out, hseq);
}

// Round 14
// 365.536 us; speedup vs baseline: 5.0312x; 1.0155x over previous
//
#include <hip/hip_runtime.h>
#include <hip/hip_bf16.h>

#define T_DIM 2048
#define B_DIM 16
#define D_DIM 1024
#define M_DIM (T_DIM * B_DIM)   // 32768 GEMM rows
#define K_DIM D_DIM             // 1024
#define N_DIM (3 * D_DIM)       // 3072 (cand_x | delta | gate)
#define BD (B_DIM * D_DIM)      // 16384 parallel chains
#define CHUNKS 64
#define CLEN (T_DIM / CHUNKS)   // 32
#define NT (K_DIM / 64)         // 16 K-tiles (BK=64)

typedef __attribute__((ext_vector_type(8))) short bf16x8;
typedef __attribute__((ext_vector_type(4))) float f32x4;
typedef __attribute__((ext_vector_type(4))) unsigned short us4;
typedef __attribute__((ext_vector_type(8))) unsigned short us8;

__device__ __forceinline__ unsigned short f2bf(float f) {
    unsigned int u = __builtin_bit_cast(unsigned int, f);
    u += 0x7fffu + ((u >> 16) & 1u);  // RNE
    return (unsigned short)(u >> 16);
}
__device__ __forceinline__ float bf2f(unsigned short s) {
    unsigned int u = ((unsigned int)s) << 16;
    return __builtin_bit_cast(float, u);
}
__device__ __forceinline__ float sigmoid_f(float x) {
    return __builtin_amdgcn_rcpf(1.0f + __expf(-x));
}
__device__ __forceinline__ float tanh_f(float x) {
    float e = __expf(2.0f * x);
    return 1.0f - 2.0f * __builtin_amdgcn_rcpf(e + 1.0f);
}

// verified primitive: offset immediate ALWAYS 0 (nonzero was the R13 bug)
__device__ __forceinline__ void gload_lds16(const unsigned short* g, unsigned short* l) {
    __builtin_amdgcn_global_load_lds(
        (const __attribute__((address_space(1))) unsigned int*)g,
        (__attribute__((address_space(3))) unsigned int*)l, 16, 0, 0);
}

// ---------------------------------------------------------------------------
// Single merged f32 -> bf16 conversion for x, Wx, Wd, Wg (1 launch).
// ---------------------------------------------------------------------------
#define XN8 (M_DIM * K_DIM / 8)
#define WN8 (D_DIM * K_DIM / 8)
__global__ __launch_bounds__(256)
void conv_all(const float* __restrict__ x,  const float* __restrict__ Wx,
              const float* __restrict__ Wd, const float* __restrict__ Wg,
              unsigned short* __restrict__ xb, unsigned short* __restrict__ Wb)
{
    int i = blockIdx.x * 256 + threadIdx.x;
    const float* src;
    unsigned short* dst;
    int off;
    if (i < XN8)                { src = x;  dst = xb;               off = i; }
    else if (i < XN8 + WN8)     { src = Wx; dst = Wb;               off = i - XN8; }
    else if (i < XN8 + 2 * WN8) { src = Wd; dst = Wb + (size_t)WN8 * 8;     off = i - XN8 - WN8; }
    else                        { src = Wg; dst = Wb + (size_t)2 * WN8 * 8; off = i - XN8 - 2 * WN8; }
    const f32x4* p = reinterpret_cast<const f32x4*>(src) + (size_t)off * 2;
    f32x4 v0 = __builtin_nontemporal_load(p);
    f32x4 v1 = __builtin_nontemporal_load(p + 1);
    us8 w;
    w[0] = f2bf(v0[0]); w[1] = f2bf(v0[1]); w[2] = f2bf(v0[2]); w[3] = f2bf(v0[3]);
    w[4] = f2bf(v1[0]); w[5] = f2bf(v1[1]); w[6] = f2bf(v1[2]); w[7] = f2bf(v1[3]);
    *reinterpret_cast<us8*>(dst + (size_t)off * 8) = w;
}

// ---------------------------------------------------------------------------
// Fused projection GEMM — 256x256 tile, BK=64, 8 waves (2Mx4N).
// R12's verified 2-barrier schedule with the K-loop fully unrolled and all
// addressing hoisted: 8 per-lane global base pointers (tile offset folded as
// a LITERAL pointer add, builtin offset stays 0) and precomputed ds_read
// offsets so slot/m4/ni fold into immediates. Minimal per-tile VALU.
// ---------------------------------------------------------------------------
__global__ __launch_bounds__(512, 2)
void gemm_fused(const unsigned short* __restrict__ xb,
                const unsigned short* __restrict__ Wb,
                const float* __restrict__ bx, const float* __restrict__ bdl,
                const float* __restrict__ bg,
                unsigned short* __restrict__ cxw, unsigned short* __restrict__ dw,
                unsigned short* __restrict__ gw)
{
    // 128 KiB LDS: K-loop = 4 half-slots x 16KB per operand; epilogue = C-tile
    __shared__ unsigned short lds[8 * 8192];
    unsigned short* ldsA = lds;
    unsigned short* ldsB = lds + 4 * 8192;

    const int NWG = (M_DIM / 256) * (N_DIM / 256);   // 1536, %8 == 0
    int bid = blockIdx.x;
    int wg  = (bid & 7) * (NWG / 8) + (bid >> 3);    // XCD-bijective
    const int bidM = wg / 12;                        // M-outer per XCD
    const int bidN = wg % 12;                        // N inner: x-panel L2-resident
    const int tM  = bidM * 256;
    const int tN  = bidN * 256;
    const int arr = tN >> 10;
    const int nb  = tN & 1023;

    const float* bias = (arr == 0) ? bx : (arr == 1) ? bdl : bg;
    unsigned short* outp = (arr == 0) ? cxw : (arr == 1) ? dw : gw;

    const int tid  = threadIdx.x;
    const int lane = tid & 63;
    const int wid  = tid >> 6;
    const int wr = wid >> 2, wc = wid & 3;           // wave -> 128x64 output
    const int lr = lane & 15, lk = lane >> 4;

    const unsigned short* Asrc = xb + (size_t)tM * K_DIM;
    const unsigned short* Bsrc = Wb + (size_t)arr * (D_DIM * K_DIM) + (size_t)nb * K_DIM;

    // staging source geometry (T2 inverse swizzle on the global address)
    const int t8 = tid >> 3;                              // 0..63
    const int ke = (((tid & 7) ^ (t8 & 7)) << 3);         // k-elem offset
    auto arow = [&](int h, int w) {
        int s = w * 64 + t8;
        return ((s >> 4) & 1) * 128 + (h * 4 + (s >> 5)) * 16 + (s & 15);
    };
    // 8 hoisted per-lane global base pointers (ke folded in)
    const unsigned short* gA0 = Asrc + (size_t)arow(0, 0) * K_DIM + ke;
    const unsigned short* gA1 = Asrc + (size_t)arow(0, 1) * K_DIM + ke;
    const unsigned short* gA2 = Asrc + (size_t)arow(1, 0) * K_DIM + ke;
    const unsigned short* gA3 = Asrc + (size_t)arow(1, 1) * K_DIM + ke;
    const unsigned short* gB0 = Bsrc + (size_t)(t8)       * K_DIM + ke;
    const unsigned short* gB1 = Bsrc + (size_t)(64 + t8)  * K_DIM + ke;
    const unsigned short* gB2 = Bsrc + (size_t)(128 + t8) * K_DIM + ke;
    const unsigned short* gB3 = Bsrc + (size_t)(192 + t8) * K_DIM + ke;
    // LDS staging destinations (wave-uniform)
    unsigned short* dA0 = ldsA + wid * 512;
    unsigned short* dA1 = ldsA + 4096 + wid * 512;
    unsigned short* dB0 = ldsB + wid * 512;
    unsigned short* dB1 = ldsB + 4096 + wid * 512;

    // ds_read per-thread base offsets (elements); slot/m4/ni fold to imm.
    const int swz = (lr & 7) << 4;                        // byte XOR term
    const int ce0 = ((lk * 16) ^ swz) >> 1;               // kk = 0
    const int ce1 = (((64) + lk * 16) ^ swz) >> 1;        // kk = 1
    const int aB0 = (wr * 16 + lr) * 64 + ce0;
    const int aB1 = (wr * 16 + lr) * 64 + ce1;
    const int brow = (wc & 1) * 64;
    const int bB0 = (wc >> 1) * 8192 + (brow + lr) * 64 + ce0;
    const int bB1 = (wc >> 1) * 8192 + (brow + lr) * 64 + ce1;

    f32x4 acc[8][4];
#pragma unroll
    for (int mi = 0; mi < 8; mi++)
#pragma unroll
        for (int ni = 0; ni < 4; ni++)
            acc[mi][ni] = (f32x4){0.f, 0.f, 0.f, 0.f};

// T is a compile-time literal in every expansion -> the +T*64 folds into the
// address constant; builtin's immediate offset stays 0 (verified path).
#define STA0(T, SLOT) do { gload_lds16(gA0 + (T) * 64, dA0 + (SLOT) * 8192); \
                           gload_lds16(gA1 + (T) * 64, dA1 + (SLOT) * 8192); } while (0)
#define STA1(T, SLOT) do { gload_lds16(gA2 + (T) * 64, dA0 + (SLOT) * 8192); \
                           gload_lds16(gA3 + (T) * 64, dA1 + (SLOT) * 8192); } while (0)
#define STB0(T, SLOT) do { gload_lds16(gB0 + (T) * 64, dB0 + (SLOT) * 8192); \
                           gload_lds16(gB1 + (T) * 64, dB1 + (SLOT) * 8192); } while (0)
#define STB1(T, SLOT) do { gload_lds16(gB2 + (T) * 64, dB0 + (SLOT) * 8192); \
                           gload_lds16(gB3 + (T) * 64, dB1 + (SLOT) * 8192); } while (0)

    // Prologue: tile0 (4 halves) + tile1 {A0, B0, B1} => 14 loads/wave
    STA0(0, 0);
    STA1(0, 1);
    STB0(0, 0);
    STB1(0, 1);
    STA0(1, 2);
    STB0(1, 2);
    STB1(1, 3);
    asm volatile("s_waitcnt vmcnt(0)" ::: "memory");
    __builtin_amdgcn_s_barrier();

    bf16x8 bf[4][2], af[4][2];

#define RD_AF8(ASLOT)                                                              \
    do {                                                                           \
        _Pragma("unroll") for (int m4 = 0; m4 < 4; m4++) {                         \
            af[m4][0] = *reinterpret_cast<const bf16x8*>(                          \
                ldsA + (ASLOT) * 8192 + m4 * 2048 + aB0);                          \
            af[m4][1] = *reinterpret_cast<const bf16x8*>(                          \
                ldsA + (ASLOT) * 8192 + m4 * 2048 + aB1);                          \
        }                                                                          \
    } while (0)

#define RD_BF(PARN)                                                                \
    do {                                                                           \
        _Pragma("unroll") for (int ni = 0; ni < 4; ni++) {                         \
            bf[ni][0] = *reinterpret_cast<const bf16x8*>(                          \
                ldsB + 2 * (PARN) * 8192 + ni * 1024 + bB0);                       \
            bf[ni][1] = *reinterpret_cast<const bf16x8*>(                          \
                ldsB + 2 * (PARN) * 8192 + ni * 1024 + bB1);                       \
        }                                                                          \
    } while (0)

// operand-swapped: acc = bf * af => acc holds C^T quadrants. 32 MFMA cluster.
#define MFMA32(HALF)                                                               \
    do {                                                                           \
        __builtin_amdgcn_s_setprio(1);                                             \
        _Pragma("unroll") for (int m4 = 0; m4 < 4; m4++)                           \
            _Pragma("unroll") for (int ni = 0; ni < 4; ni++) {                     \
                acc[(HALF) * 4 + m4][ni] = __builtin_amdgcn_mfma_f32_16x16x32_bf16( \
                    bf[ni][0], af[m4][0], acc[(HALF) * 4 + m4][ni], 0, 0, 0);      \
                acc[(HALF) * 4 + m4][ni] = __builtin_amdgcn_mfma_f32_16x16x32_bf16( \
                    bf[ni][1], af[m4][1], acc[(HALF) * 4 + m4][ni], 0, 0, 0);      \
            }                                                                      \
        __builtin_amdgcn_s_setprio(0);                                             \
    } while (0)

#define BAR __builtin_amdgcn_s_barrier()

// Schedule and hazard ledger identical to the verified R12 kernel; KT is a
// LITERAL in every expansion, so stage conditions/offsets are compile-time.
#define TILE(KT, PAR, LAST)                                                        \
    do {                                                                           \
        /* P0: stage A(t+1,h1); read af(h0); 32 MFMA (mi0-3) */                    \
        if ((KT) + 1 < NT) STA1((KT) + 1, 2 * (1 - (PAR)) + 1);                    \
        RD_AF8(2 * (PAR));                                                         \
        MFMA32(0);                                                                 \
        BAR;                                                                       \
        /* P1: stage A/B(t+2); read af(h1); 32 MFMA (mi4-7); vmcnt; BAR; bf */     \
        if ((KT) + 2 < NT) {                                                       \
            STA0((KT) + 2, 2 * (PAR));                                             \
            STB0((KT) + 2, 2 * (PAR));                                             \
            STB1((KT) + 2, 2 * (PAR) + 1);                                         \
        }                                                                          \
        RD_AF8(2 * (PAR) + 1);                                                     \
        MFMA32(1);                                                                 \
        if ((KT) < NT - 2) asm volatile("s_waitcnt vmcnt(6)" ::: "memory");        \
        else               asm volatile("s_waitcnt vmcnt(0)" ::: "memory");        \
        BAR;                                                                       \
        if (!(LAST)) RD_BF(1 - (PAR));                                             \
    } while (0)

    // initial bf fill for tile 0 (B slot base 0, par = 0)
    RD_BF(0);

    TILE(0, 0, false);  TILE(1, 1, false);
    TILE(2, 0, false);  TILE(3, 1, false);
    TILE(4, 0, false);  TILE(5, 1, false);
    TILE(6, 0, false);  TILE(7, 1, false);
    TILE(8, 0, false);  TILE(9, 1, false);
    TILE(10, 0, false); TILE(11, 1, false);
    TILE(12, 0, false); TILE(13, 1, false);
    TILE(14, 0, false); TILE(15, 1, true);

    // ---- Epilogue: acc = C^T quadrants -> packed b64 swizzled LDS stores,
    //      then fully-coalesced nontemporal 16B global stores.
#pragma unroll
    for (int mi = 0; mi < 8; mi++) {
        int row = wr * 128 + mi * 16 + lr;        // C-row (local 0..255)
#pragma unroll
        for (int ni = 0; ni < 4; ni++) {
            int col0 = wc * 64 + ni * 16 + lk * 4; // 4 consecutive C-cols
            f32x4 bia = *reinterpret_cast<const f32x4*>(bias + nb + col0);
            us4 w;
#pragma unroll
            for (int r = 0; r < 4; r++) {
                float v = acc[mi][ni][r] + bia[r];
                if (arr == 1)      v = sigmoid_f(v);
                else if (arr == 2) v = v * sigmoid_f(v);
                w[r] = f2bf(v);
            }
            int byte = (row * 512 + col0 * 2) ^ ((row & 7) << 4);
            *reinterpret_cast<us4*>(reinterpret_cast<char*>(lds) + byte) = w;
        }
    }
    __syncthreads();
#pragma unroll
    for (int it = 0; it < 16; ++it) {
        int off8 = it * 512 + tid;              // 16B-chunk id, 8192 total
        int row  = off8 >> 5;                   // 32 chunks per 256-col row
        int col8 = (off8 & 31) << 3;
        int byte = (row * 512 + col8 * 2) ^ ((row & 7) << 4);
        us8 v = *reinterpret_cast<const us8*>(reinterpret_cast<char*>(lds) + byte);
        __builtin_nontemporal_store(v,
            reinterpret_cast<us8*>(outp + (size_t)(tM + row) * D_DIM + nb + col8));
    }
#undef STA0
#undef STA1
#undef STB0
#undef STB1
#undef RD_AF8
#undef RD_BF
#undef MFMA32
#undef BAR
#undef TILE
}

// ---------------------------------------------------------------------------
// Scan pass 1: per (chunk, channel-quad): A = prod(1-d), B = local scan from 0
// ---------------------------------------------------------------------------
__global__ __launch_bounds__(256)
void scan_pass1(const unsigned short* __restrict__ dw,
                const unsigned short* __restrict__ cxw,
                float* __restrict__ Aw, float* __restrict__ Bw)
{
    int g  = blockIdx.x * 256 + threadIdx.x;
    int c  = g / (BD / 4);
    int i0 = (g % (BD / 4)) * 4;
    size_t base = (size_t)c * CLEN * BD + i0;

    float a[4]  = {1.f, 1.f, 1.f, 1.f};
    float hb[4] = {0.f, 0.f, 0.f, 0.f};
    for (int t = 0; t < CLEN; t++) {
        us4 dv = *reinterpret_cast<const us4*>(dw  + base + (size_t)t * BD);
        us4 cv = *reinterpret_cast<const us4*>(cxw + base + (size_t)t * BD);
#pragma unroll
        for (int j = 0; j < 4; j++) {
            float d = bf2f(dv[j]);
            float om = 1.f - d;
            float cand = tanh_f(bf2f(cv[j]));
            hb[j] = om * hb[j] + d * cand;
            a[j] *= om;
        }
    }
    f32x4 av = {a[0], a[1], a[2], a[3]};
    f32x4 bv = {hb[0], hb[1], hb[2], hb[3]};
    *reinterpret_cast<f32x4*>(Aw + (size_t)c * BD + i0) = av;
    *reinterpret_cast<f32x4*>(Bw + (size_t)c * BD + i0) = bv;
}

// ---------------------------------------------------------------------------
// Scan pass 2: sequential combine over chunks (tiny). Writes h[0].
// ---------------------------------------------------------------------------
__global__ __launch_bounds__(256)
void scan_pass2(const float* __restrict__ Aw, const float* __restrict__ Bw,
                const float* __restrict__ h0, float* __restrict__ hin,
                float* __restrict__ hseq)
{
    int i0 = (blockIdx.x * 256 + threadIdx.x) * 4;
    if (i0 >= BD) return;
    f32x4 h = *reinterpret_cast<const f32x4*>(h0 + i0);
    *reinterpret_cast<f32x4*>(hseq + i0) = h;
    for (int c = 0; c < CHUNKS; c++) {
        *reinterpret_cast<f32x4*>(hin + (size_t)c * BD + i0) = h;
        f32x4 A  = *reinterpret_cast<const f32x4*>(Aw + (size_t)c * BD + i0);
        f32x4 Bv = *reinterpret_cast<const f32x4*>(Bw + (size_t)c * BD + i0);
        h = A * h + Bv;
    }
}

// ---------------------------------------------------------------------------
// Scan pass 3: replay each chunk with true h_in; nt-store out and h.
// ---------------------------------------------------------------------------
__global__ __launch_bounds__(256)
void scan_pass3(const unsigned short* __restrict__ dw,
                const unsigned short* __restrict__ cxw,
                const unsigned short* __restrict__ gw,
                const float* __restrict__ hin,
                float* __restrict__ out, float* __restrict__ hseq)
{
    int g  = blockIdx.x * 256 + threadIdx.x;
    int c  = g / (BD / 4);
    int i0 = (g % (BD / 4)) * 4;
    size_t base = (size_t)c * CLEN * BD + i0;

    f32x4 h4 = *reinterpret_cast<const f32x4*>(hin + (size_t)c * BD + i0);
    float h[4] = {h4[0], h4[1], h4[2], h4[3]};
    for (int t = 0; t < CLEN; t++) {
        size_t idx = base + (size_t)t * BD;
        us4 dv = *reinterpret_cast<const us4*>(dw  + idx);
        us4 cv = *reinterpret_cast<const us4*>(cxw + idx);
        us4 gv = *reinterpret_cast<const us4*>(gw  + idx);
        f32x4 o, hv;
#pragma unroll
        for (int j = 0; j < 4; j++) {
            float d = bf2f(dv[j]);
            float om = 1.f - d;
            float cand = tanh_f(bf2f(cv[j]));
            h[j] = om * h[j] + d * cand;
            o[j] = h[j] * bf2f(gv[j]);
            hv[j] = h[j];
        }
        __builtin_nontemporal_store(o,  reinterpret_cast<f32x4*>(out + idx));
        __builtin_nontemporal_store(hv, reinterpret_cast<f32x4*>(hseq + idx + BD));
    }
}

// ---------------------------------------------------------------------------
// Fixup for channels with r_h != 0 (r_h == 0 here -> immediate exit).
// ---------------------------------------------------------------------------
__global__ __launch_bounds__(256)
void scan_fixup(const float* __restrict__ rh, const float* __restrict__ h0,
                const unsigned short* __restrict__ dw,
                const unsigned short* __restrict__ cxw,
                const unsigned short* __restrict__ gw,
                float* __restrict__ out, float* __restrict__ hseq)
{
    int i = blockIdx.x * 256 + threadIdx.x;
    if (i >= BD) return;
    float r = rh[i & (D_DIM - 1)];
    if (r == 0.0f) return;
    float h = h0[i];
    for (int t = 0; t < T_DIM; t++) {
        size_t idx = (size_t)t * BD + i;
        float d = bf2f(dw[idx]);
        float cand = tanh_f(bf2f(cxw[idx]) + r * h);
        h = (1.f - d) * h + d * cand;
        out[idx] = h * bf2f(gw[idx]);
        hseq[idx + BD] = h;
    }
}

extern "C" void kernel_launch(void* const* d_in, const int* in_sizes, int n_in,
                              void* d_out, int out_size, void* d_ws, size_t ws_size,
                              hipStream_t stream)
{
    const float* x   = (const float*)d_in[0];
    const float* h0  = (const float*)d_in[1];
    const float* Wx  = (const float*)d_in[2];
    const float* rh  = (const float*)d_in[3];
    const float* Wd  = (const float*)d_in[4];
    const float* Wg  = (const float*)d_in[5];
    const float* bx  = (const float*)d_in[6];
    const float* bdl = (const float*)d_in[7];
    const float* bg  = (const float*)d_in[8];

    float* out  = (float*)d_out;                       // [T,B,D]
    float* hseq = out + (size_t)T_DIM * BD;            // [T+1,B,D]

    unsigned short* dw  = (unsigned short*)d_ws;
    unsigned short* cxw = dw  + (size_t)M_DIM * D_DIM;
    unsigned short* gw  = cxw + (size_t)M_DIM * D_DIM;
    float* Aw  = (float*)(gw + (size_t)M_DIM * D_DIM);
    float* Bw  = Aw + (size_t)CHUNKS * BD;
    float* hin = Bw + (size_t)CHUNKS * BD;

    // bf16 x and W live in the not-yet-written `out` region (GEMM finishes
    // before scan_pass3 writes out). 67.1 MB + 6.3 MB < 134 MB.
    unsigned short* xb = (unsigned short*)d_out;
    unsigned short* Wb = xb + (size_t)M_DIM * K_DIM;

    conv_all<<<dim3((XN8 + 3 * WN8) / 256), dim3(256), 0, stream>>>(x, Wx, Wd, Wg, xb, Wb);

    gemm_fused<<<dim3((M_DIM / 256) * (N_DIM / 256)), dim3(512), 0, stream>>>(
        xb, Wb, bx, bdl, bg, cxw, dw, gw);

    scan_pass1<<<dim3(CHUNKS * BD / 4 / 256), dim3(256), 0, stream>>>(dw, cxw, Aw, Bw);
    scan_pass2<<<dim3(BD / 4 / 256 + 1), dim3(256), 0, stream>>>(Aw, Bw, h0, hin, hseq);
    scan_pass3<<<dim3(CHUNKS * BD / 4 / 256), dim3(256), 0, stream>>>(dw, cxw, gw, hin, out, hseq);
    scan_fixup<<<dim3(BD / 256), dim3(256), 0, stream>>>(rh, h0, dw, cxw, gw, out, hseq);
}

// Round 15
// 364.335 us; speedup vs baseline: 5.0478x; 1.0033x over previous
//
#include <hip/hip_runtime.h>
#include <hip/hip_bf16.h>

#define T_DIM 2048
#define B_DIM 16
#define D_DIM 1024
#define M_DIM (T_DIM * B_DIM)   // 32768 GEMM rows
#define K_DIM D_DIM             // 1024
#define N_DIM (3 * D_DIM)       // 3072 (cand_x | delta | gate)
#define BD (B_DIM * D_DIM)      // 16384 parallel chains
#define CHUNKS 64
#define CLEN (T_DIM / CHUNKS)   // 32
#define NT (K_DIM / 64)         // 16 K-tiles (BK=64)

typedef __attribute__((ext_vector_type(8))) short bf16x8;
typedef __attribute__((ext_vector_type(4))) float f32x4;
typedef __attribute__((ext_vector_type(4))) unsigned short us4;
typedef __attribute__((ext_vector_type(8))) unsigned short us8;

__device__ __forceinline__ unsigned short f2bf(float f) {
    unsigned int u = __builtin_bit_cast(unsigned int, f);
    u += 0x7fffu + ((u >> 16) & 1u);  // RNE
    return (unsigned short)(u >> 16);
}
__device__ __forceinline__ float bf2f(unsigned short s) {
    unsigned int u = ((unsigned int)s) << 16;
    return __builtin_bit_cast(float, u);
}
__device__ __forceinline__ float sigmoid_f(float x) {
    return __builtin_amdgcn_rcpf(1.0f + __expf(-x));
}
__device__ __forceinline__ float tanh_f(float x) {
    float e = __expf(2.0f * x);
    return 1.0f - 2.0f * __builtin_amdgcn_rcpf(e + 1.0f);
}

// verified primitive: offset immediate ALWAYS 0 (nonzero was the R13 bug)
__device__ __forceinline__ void gload_lds16(const unsigned short* g, unsigned short* l) {
    __builtin_amdgcn_global_load_lds(
        (const __attribute__((address_space(1))) unsigned int*)g,
        (__attribute__((address_space(3))) unsigned int*)l, 16, 0, 0);
}

// ---------------------------------------------------------------------------
// Single merged f32 -> bf16 conversion for x, Wx, Wd, Wg (1 launch).
// ---------------------------------------------------------------------------
#define XN8 (M_DIM * K_DIM / 8)
#define WN8 (D_DIM * K_DIM / 8)
__global__ __launch_bounds__(256)
void conv_all(const float* __restrict__ x,  const float* __restrict__ Wx,
              const float* __restrict__ Wd, const float* __restrict__ Wg,
              unsigned short* __restrict__ xb, unsigned short* __restrict__ Wb)
{
    int i = blockIdx.x * 256 + threadIdx.x;
    const float* src;
    unsigned short* dst;
    int off;
    if (i < XN8)                { src = x;  dst = xb;               off = i; }
    else if (i < XN8 + WN8)     { src = Wx; dst = Wb;               off = i - XN8; }
    else if (i < XN8 + 2 * WN8) { src = Wd; dst = Wb + (size_t)WN8 * 8;     off = i - XN8 - WN8; }
    else                        { src = Wg; dst = Wb + (size_t)2 * WN8 * 8; off = i - XN8 - 2 * WN8; }
    const f32x4* p = reinterpret_cast<const f32x4*>(src) + (size_t)off * 2;
    f32x4 v0 = __builtin_nontemporal_load(p);
    f32x4 v1 = __builtin_nontemporal_load(p + 1);
    us8 w;
    w[0] = f2bf(v0[0]); w[1] = f2bf(v0[1]); w[2] = f2bf(v0[2]); w[3] = f2bf(v0[3]);
    w[4] = f2bf(v1[0]); w[5] = f2bf(v1[1]); w[6] = f2bf(v1[2]); w[7] = f2bf(v1[3]);
    *reinterpret_cast<us8*>(dst + (size_t)off * 8) = w;
}

// ---------------------------------------------------------------------------
// Fused projection GEMM — 256x256 tile, BK=64, 8 waves (2Mx4N).
// Verified R14 kernel with ONE change: the prologue drains with vmcnt(6)
// (tile0's 8 loads retired, tile1's 6 prefetch loads stay in flight) instead
// of vmcnt(0). Tile1's loads are drained by TILE(0)'s P1 vmcnt(6) before
// RD_BF(tile1) — counted ledger verified.
// ---------------------------------------------------------------------------
__global__ __launch_bounds__(512, 2)
void gemm_fused(const unsigned short* __restrict__ xb,
                const unsigned short* __restrict__ Wb,
                const float* __restrict__ bx, const float* __restrict__ bdl,
                const float* __restrict__ bg,
                unsigned short* __restrict__ cxw, unsigned short* __restrict__ dw,
                unsigned short* __restrict__ gw)
{
    // 128 KiB LDS: K-loop = 4 half-slots x 16KB per operand; epilogue = C-tile
    __shared__ unsigned short lds[8 * 8192];
    unsigned short* ldsA = lds;
    unsigned short* ldsB = lds + 4 * 8192;

    const int NWG = (M_DIM / 256) * (N_DIM / 256);   // 1536, %8 == 0
    int bid = blockIdx.x;
    int wg  = (bid & 7) * (NWG / 8) + (bid >> 3);    // XCD-bijective
    const int bidM = wg / 12;                        // M-outer per XCD
    const int bidN = wg % 12;                        // N inner: x-panel L2-resident
    const int tM  = bidM * 256;
    const int tN  = bidN * 256;
    const int arr = tN >> 10;
    const int nb  = tN & 1023;

    const float* bias = (arr == 0) ? bx : (arr == 1) ? bdl : bg;
    unsigned short* outp = (arr == 0) ? cxw : (arr == 1) ? dw : gw;

    const int tid  = threadIdx.x;
    const int lane = tid & 63;
    const int wid  = tid >> 6;
    const int wr = wid >> 2, wc = wid & 3;           // wave -> 128x64 output
    const int lr = lane & 15, lk = lane >> 4;

    const unsigned short* Asrc = xb + (size_t)tM * K_DIM;
    const unsigned short* Bsrc = Wb + (size_t)arr * (D_DIM * K_DIM) + (size_t)nb * K_DIM;

    // staging source geometry (T2 inverse swizzle on the global address)
    const int t8 = tid >> 3;                              // 0..63
    const int ke = (((tid & 7) ^ (t8 & 7)) << 3);         // k-elem offset
    auto arow = [&](int h, int w) {
        int s = w * 64 + t8;
        return ((s >> 4) & 1) * 128 + (h * 4 + (s >> 5)) * 16 + (s & 15);
    };
    // 8 hoisted per-lane global base pointers (ke folded in)
    const unsigned short* gA0 = Asrc + (size_t)arow(0, 0) * K_DIM + ke;
    const unsigned short* gA1 = Asrc + (size_t)arow(0, 1) * K_DIM + ke;
    const unsigned short* gA2 = Asrc + (size_t)arow(1, 0) * K_DIM + ke;
    const unsigned short* gA3 = Asrc + (size_t)arow(1, 1) * K_DIM + ke;
    const unsigned short* gB0 = Bsrc + (size_t)(t8)       * K_DIM + ke;
    const unsigned short* gB1 = Bsrc + (size_t)(64 + t8)  * K_DIM + ke;
    const unsigned short* gB2 = Bsrc + (size_t)(128 + t8) * K_DIM + ke;
    const unsigned short* gB3 = Bsrc + (size_t)(192 + t8) * K_DIM + ke;
    // LDS staging destinations (wave-uniform)
    unsigned short* dA0 = ldsA + wid * 512;
    unsigned short* dA1 = ldsA + 4096 + wid * 512;
    unsigned short* dB0 = ldsB + wid * 512;
    unsigned short* dB1 = ldsB + 4096 + wid * 512;

    // ds_read per-thread base offsets (elements); slot/m4/ni fold to imm.
    const int swz = (lr & 7) << 4;                        // byte XOR term
    const int ce0 = ((lk * 16) ^ swz) >> 1;               // kk = 0
    const int ce1 = (((64) + lk * 16) ^ swz) >> 1;        // kk = 1
    const int aB0 = (wr * 16 + lr) * 64 + ce0;
    const int aB1 = (wr * 16 + lr) * 64 + ce1;
    const int brow = (wc & 1) * 64;
    const int bB0 = (wc >> 1) * 8192 + (brow + lr) * 64 + ce0;
    const int bB1 = (wc >> 1) * 8192 + (brow + lr) * 64 + ce1;

    f32x4 acc[8][4];
#pragma unroll
    for (int mi = 0; mi < 8; mi++)
#pragma unroll
        for (int ni = 0; ni < 4; ni++)
            acc[mi][ni] = (f32x4){0.f, 0.f, 0.f, 0.f};

// T is a compile-time literal in every expansion -> the +T*64 folds into the
// address constant; builtin's immediate offset stays 0 (verified path).
#define STA0(T, SLOT) do { gload_lds16(gA0 + (T) * 64, dA0 + (SLOT) * 8192); \
                           gload_lds16(gA1 + (T) * 64, dA1 + (SLOT) * 8192); } while (0)
#define STA1(T, SLOT) do { gload_lds16(gA2 + (T) * 64, dA0 + (SLOT) * 8192); \
                           gload_lds16(gA3 + (T) * 64, dA1 + (SLOT) * 8192); } while (0)
#define STB0(T, SLOT) do { gload_lds16(gB0 + (T) * 64, dB0 + (SLOT) * 8192); \
                           gload_lds16(gB1 + (T) * 64, dB1 + (SLOT) * 8192); } while (0)
#define STB1(T, SLOT) do { gload_lds16(gB2 + (T) * 64, dB0 + (SLOT) * 8192); \
                           gload_lds16(gB3 + (T) * 64, dB1 + (SLOT) * 8192); } while (0)

    // Prologue: tile0's 8 loads FIRST, then tile1's 6 prefetch loads.
    STA0(0, 0);
    STA1(0, 1);
    STB0(0, 0);
    STB1(0, 1);
    STA0(1, 2);
    STB0(1, 2);
    STB1(1, 3);
    // drain tile0 (8 loads); keep tile1's 6 in flight (R7-verified pattern)
    asm volatile("s_waitcnt vmcnt(6)" ::: "memory");
    __builtin_amdgcn_s_barrier();

    bf16x8 bf[4][2], af[4][2];

#define RD_AF8(ASLOT)                                                              \
    do {                                                                           \
        _Pragma("unroll") for (int m4 = 0; m4 < 4; m4++) {                         \
            af[m4][0] = *reinterpret_cast<const bf16x8*>(                          \
                ldsA + (ASLOT) * 8192 + m4 * 2048 + aB0);                          \
            af[m4][1] = *reinterpret_cast<const bf16x8*>(                          \
                ldsA + (ASLOT) * 8192 + m4 * 2048 + aB1);                          \
        }                                                                          \
    } while (0)

#define RD_BF(PARN)                                                                \
    do {                                                                           \
        _Pragma("unroll") for (int ni = 0; ni < 4; ni++) {                         \
            bf[ni][0] = *reinterpret_cast<const bf16x8*>(                          \
                ldsB + 2 * (PARN) * 8192 + ni * 1024 + bB0);                       \
            bf[ni][1] = *reinterpret_cast<const bf16x8*>(                          \
                ldsB + 2 * (PARN) * 8192 + ni * 1024 + bB1);                       \
        }                                                                          \
    } while (0)

// operand-swapped: acc = bf * af => acc holds C^T quadrants. 32 MFMA cluster.
#define MFMA32(HALF)                                                               \
    do {                                                                           \
        __builtin_amdgcn_s_setprio(1);                                             \
        _Pragma("unroll") for (int m4 = 0; m4 < 4; m4++)                           \
            _Pragma("unroll") for (int ni = 0; ni < 4; ni++) {                     \
                acc[(HALF) * 4 + m4][ni] = __builtin_amdgcn_mfma_f32_16x16x32_bf16( \
                    bf[ni][0], af[m4][0], acc[(HALF) * 4 + m4][ni], 0, 0, 0);      \
                acc[(HALF) * 4 + m4][ni] = __builtin_amdgcn_mfma_f32_16x16x32_bf16( \
                    bf[ni][1], af[m4][1], acc[(HALF) * 4 + m4][ni], 0, 0, 0);      \
            }                                                                      \
        __builtin_amdgcn_s_setprio(0);                                             \
    } while (0)

#define BAR __builtin_amdgcn_s_barrier()

// Schedule and hazard ledger identical to the verified R12/R14 kernel; KT is
// a LITERAL in every expansion, so stage conditions/offsets are compile-time.
// Prologue vmcnt(6) note: tile1's 6 loads are drained by TILE(0)'s P1
// vmcnt(6) (which retains only P1's own 6 stages) + BAR, before RD_BF(1).
#define TILE(KT, PAR, LAST)                                                        \
    do {                                                                           \
        /* P0: stage A(t+1,h1); read af(h0); 32 MFMA (mi0-3) */                    \
        if ((KT) + 1 < NT) STA1((KT) + 1, 2 * (1 - (PAR)) + 1);                    \
        RD_AF8(2 * (PAR));                                                         \
        MFMA32(0);                                                                 \
        BAR;                                                                       \
        /* P1: stage A/B(t+2); read af(h1); 32 MFMA (mi4-7); vmcnt; BAR; bf */     \
        if ((KT) + 2 < NT) {                                                       \
            STA0((KT) + 2, 2 * (PAR));                                             \
            STB0((KT) + 2, 2 * (PAR));                                             \
            STB1((KT) + 2, 2 * (PAR) + 1);                                         \
        }                                                                          \
        RD_AF8(2 * (PAR) + 1);                                                     \
        MFMA32(1);                                                                 \
        if ((KT) < NT - 2) asm volatile("s_waitcnt vmcnt(6)" ::: "memory");        \
        else               asm volatile("s_waitcnt vmcnt(0)" ::: "memory");        \
        BAR;                                                                       \
        if (!(LAST)) RD_BF(1 - (PAR));                                             \
    } while (0)

    // initial bf fill for tile 0 (B slot base 0, par = 0)
    RD_BF(0);

    TILE(0, 0, false);  TILE(1, 1, false);
    TILE(2, 0, false);  TILE(3, 1, false);
    TILE(4, 0, false);  TILE(5, 1, false);
    TILE(6, 0, false);  TILE(7, 1, false);
    TILE(8, 0, false);  TILE(9, 1, false);
    TILE(10, 0, false); TILE(11, 1, false);
    TILE(12, 0, false); TILE(13, 1, false);
    TILE(14, 0, false); TILE(15, 1, true);

    // ---- Epilogue: acc = C^T quadrants -> packed b64 swizzled LDS stores,
    //      then fully-coalesced nontemporal 16B global stores.
#pragma unroll
    for (int mi = 0; mi < 8; mi++) {
        int row = wr * 128 + mi * 16 + lr;        // C-row (local 0..255)
#pragma unroll
        for (int ni = 0; ni < 4; ni++) {
            int col0 = wc * 64 + ni * 16 + lk * 4; // 4 consecutive C-cols
            f32x4 bia = *reinterpret_cast<const f32x4*>(bias + nb + col0);
            us4 w;
#pragma unroll
            for (int r = 0; r < 4; r++) {
                float v = acc[mi][ni][r] + bia[r];
                if (arr == 1)      v = sigmoid_f(v);
                else if (arr == 2) v = v * sigmoid_f(v);
                w[r] = f2bf(v);
            }
            int byte = (row * 512 + col0 * 2) ^ ((row & 7) << 4);
            *reinterpret_cast<us4*>(reinterpret_cast<char*>(lds) + byte) = w;
        }
    }
    __syncthreads();
#pragma unroll
    for (int it = 0; it < 16; ++it) {
        int off8 = it * 512 + tid;              // 16B-chunk id, 8192 total
        int row  = off8 >> 5;                   // 32 chunks per 256-col row
        int col8 = (off8 & 31) << 3;
        int byte = (row * 512 + col8 * 2) ^ ((row & 7) << 4);
        us8 v = *reinterpret_cast<const us8*>(reinterpret_cast<char*>(lds) + byte);
        __builtin_nontemporal_store(v,
            reinterpret_cast<us8*>(outp + (size_t)(tM + row) * D_DIM + nb + col8));
    }
#undef STA0
#undef STA1
#undef STB0
#undef STB1
#undef RD_AF8
#undef RD_BF
#undef MFMA32
#undef BAR
#undef TILE
}

// ---------------------------------------------------------------------------
// Scan pass 1: per (chunk, channel-quad): A = prod(1-d), B = local scan from 0
// ---------------------------------------------------------------------------
__global__ __launch_bounds__(256)
void scan_pass1(const unsigned short* __restrict__ dw,
                const unsigned short* __restrict__ cxw,
                float* __restrict__ Aw, float* __restrict__ Bw)
{
    int g  = blockIdx.x * 256 + threadIdx.x;
    int c  = g / (BD / 4);
    int i0 = (g % (BD / 4)) * 4;
    size_t base = (size_t)c * CLEN * BD + i0;

    float a[4]  = {1.f, 1.f, 1.f, 1.f};
    float hb[4] = {0.f, 0.f, 0.f, 0.f};
    for (int t = 0; t < CLEN; t++) {
        us4 dv = *reinterpret_cast<const us4*>(dw  + base + (size_t)t * BD);
        us4 cv = *reinterpret_cast<const us4*>(cxw + base + (size_t)t * BD);
#pragma unroll
        for (int j = 0; j < 4; j++) {
            float d = bf2f(dv[j]);
            float om = 1.f - d;
            float cand = tanh_f(bf2f(cv[j]));
            hb[j] = om * hb[j] + d * cand;
            a[j] *= om;
        }
    }
    f32x4 av = {a[0], a[1], a[2], a[3]};
    f32x4 bv = {hb[0], hb[1], hb[2], hb[3]};
    *reinterpret_cast<f32x4*>(Aw + (size_t)c * BD + i0) = av;
    *reinterpret_cast<f32x4*>(Bw + (size_t)c * BD + i0) = bv;
}

// ---------------------------------------------------------------------------
// Scan pass 2: sequential combine over chunks (tiny). Writes h[0].
// ---------------------------------------------------------------------------
__global__ __launch_bounds__(256)
void scan_pass2(const float* __restrict__ Aw, const float* __restrict__ Bw,
                const float* __restrict__ h0, float* __restrict__ hin,
                float* __restrict__ hseq)
{
    int i0 = (blockIdx.x * 256 + threadIdx.x) * 4;
    if (i0 >= BD) return;
    f32x4 h = *reinterpret_cast<const f32x4*>(h0 + i0);
    *reinterpret_cast<f32x4*>(hseq + i0) = h;
    for (int c = 0; c < CHUNKS; c++) {
        *reinterpret_cast<f32x4*>(hin + (size_t)c * BD + i0) = h;
        f32x4 A  = *reinterpret_cast<const f32x4*>(Aw + (size_t)c * BD + i0);
        f32x4 Bv = *reinterpret_cast<const f32x4*>(Bw + (size_t)c * BD + i0);
        h = A * h + Bv;
    }
}

// ---------------------------------------------------------------------------
// Scan pass 3: replay each chunk with true h_in; nt-store out and h.
// ---------------------------------------------------------------------------
__global__ __launch_bounds__(256)
void scan_pass3(const unsigned short* __restrict__ dw,
                const unsigned short* __restrict__ cxw,
                const unsigned short* __restrict__ gw,
                const float* __restrict__ hin,
                float* __restrict__ out, float* __restrict__ hseq)
{
    int g  = blockIdx.x * 256 + threadIdx.x;
    int c  = g / (BD / 4);
    int i0 = (g % (BD / 4)) * 4;
    size_t base = (size_t)c * CLEN * BD + i0;

    f32x4 h4 = *reinterpret_cast<const f32x4*>(hin + (size_t)c * BD + i0);
    float h[4] = {h4[0], h4[1], h4[2], h4[3]};
    for (int t = 0; t < CLEN; t++) {
        size_t idx = base + (size_t)t * BD;
        us4 dv = *reinterpret_cast<const us4*>(dw  + idx);
        us4 cv = *reinterpret_cast<const us4*>(cxw + idx);
        us4 gv = *reinterpret_cast<const us4*>(gw  + idx);
        f32x4 o, hv;
#pragma unroll
        for (int j = 0; j < 4; j++) {
            float d = bf2f(dv[j]);
            float om = 1.f - d;
            float cand = tanh_f(bf2f(cv[j]));
            h[j] = om * h[j] + d * cand;
            o[j] = h[j] * bf2f(gv[j]);
            hv[j] = h[j];
        }
        __builtin_nontemporal_store(o,  reinterpret_cast<f32x4*>(out + idx));
        __builtin_nontemporal_store(hv, reinterpret_cast<f32x4*>(hseq + idx + BD));
    }
}

// ---------------------------------------------------------------------------
// Fixup for channels with r_h != 0 (r_h == 0 here -> immediate exit).
// ---------------------------------------------------------------------------
__global__ __launch_bounds__(256)
void scan_fixup(const float* __restrict__ rh, const float* __restrict__ h0,
                const unsigned short* __restrict__ dw,
                const unsigned short* __restrict__ cxw,
                const unsigned short* __restrict__ gw,
                float* __restrict__ out, float* __restrict__ hseq)
{
    int i = blockIdx.x * 256 + threadIdx.x;
    if (i >= BD) return;
    float r = rh[i & (D_DIM - 1)];
    if (r == 0.0f) return;
    float h = h0[i];
    for (int t = 0; t < T_DIM; t++) {
        size_t idx = (size_t)t * BD + i;
        float d = bf2f(dw[idx]);
        float cand = tanh_f(bf2f(cxw[idx]) + r * h);
        h = (1.f - d) * h + d * cand;
        out[idx] = h * bf2f(gw[idx]);
        hseq[idx + BD] = h;
    }
}

extern "C" void kernel_launch(void* const* d_in, const int* in_sizes, int n_in,
                              void* d_out, int out_size, void* d_ws, size_t ws_size,
                              hipStream_t stream)
{
    const float* x   = (const float*)d_in[0];
    const float* h0  = (const float*)d_in[1];
    const float* Wx  = (const float*)d_in[2];
    const float* rh  = (const float*)d_in[3];
    const float* Wd  = (const float*)d_in[4];
    const float* Wg  = (const float*)d_in[5];
    const float* bx  = (const float*)d_in[6];
    const float* bdl = (const float*)d_in[7];
    const float* bg  = (const float*)d_in[8];

    float* out  = (float*)d_out;                       // [T,B,D]
    float* hseq = out + (size_t)T_DIM * BD;            // [T+1,B,D]

    unsigned short* dw  = (unsigned short*)d_ws;
    unsigned short* cxw = dw  + (size_t)M_DIM * D_DIM;
    unsigned short* gw  = cxw + (size_t)M_DIM * D_DIM;
    float* Aw  = (float*)(gw + (size_t)M_DIM * D_DIM);
    float* Bw  = Aw + (size_t)CHUNKS * BD;
    float* hin = Bw + (size_t)CHUNKS * BD;

    // bf16 x and W live in the not-yet-written `out` region (GEMM finishes
    // before scan_pass3 writes out). 67.1 MB + 6.3 MB < 134 MB.
    unsigned short* xb = (unsigned short*)d_out;
    unsigned short* Wb = xb + (size_t)M_DIM * K_DIM;

    conv_all<<<dim3((XN8 + 3 * WN8) / 256), dim3(256), 0, stream>>>(x, Wx, Wd, Wg, xb, Wb);

    gemm_fused<<<dim3((M_DIM / 256) * (N_DIM / 256)), dim3(512), 0, stream>>>(
        xb, Wb, bx, bdl, bg, cxw, dw, gw);

    scan_pass1<<<dim3(CHUNKS * BD / 4 / 256), dim3(256), 0, stream>>>(dw, cxw, Aw, Bw);
    scan_pass2<<<dim3(BD / 4 / 256 + 1), dim3(256), 0, stream>>>(Aw, Bw, h0, hin, hseq);
    scan_pass3<<<dim3(CHUNKS * BD / 4 / 256), dim3(256), 0, stream>>>(dw, cxw, gw, hin, out, hseq);
    scan_fixup<<<dim3(BD / 256), dim3(256), 0, stream>>>(rh, h0, dw, cxw, gw, out, hseq);
}